// Round 9
// baseline (234.738 us; speedup 1.0000x reference)
//
#include <hip/hip_runtime.h>

// LIF forward: X [B, T, N] fp32 -> spikes [B, T, N] fp32. B=128,T=32,N=8192.
//   mem = mem + (x - mem)/2 ; spike = (mem-1 > 0) ; mem = spike ? 0 : mem
// Memory-bound: 268 MB traffic -> ~42.5 us floor at 6.3 TB/s copy ceiling.
// R1-R8 recap: every variant (scalar MLP, full occupancy TLP, forced 16-deep
//   dwordx4 burst = 16KB/wave in flight) plateaus at 2.5-2.9 TB/s. MLP and
//   width theories are falsified by R5/R8.
// Last invariant vs the 6.3+ TB/s cases (copy/fill): per-wave streams were
//   1 KB runs at 32 KB stride -> DRAM channel queues see short scattered
//   strided bursts (row thrash). R9 remaps columns so each wave's 4 loads
//   per timestep form a 4 KB SEQUENTIAL run (thread owns 4 columns at
//   lane-stride 64; every load stays unit-stride coalesced).
// Loads + s_waitcnt vmcnt(0) live in ONE asm block (R7 lesson: split
//   load/wait asm lets regalloc copy registers before data lands).

#define T_STEPS 32
#define N4 2048            // N/4 (float4 units per row)
#define TN4 (T_STEPS * N4) // float4 units per b

__device__ __forceinline__ float4 lif_step4(const float4 x, float* m) {
    float4 s;
    // exact reference order: mem += (x - mem) * 0.5 ; threshold 1.0
    m[0] = m[0] + (x.x - m[0]) * 0.5f;
    m[1] = m[1] + (x.y - m[1]) * 0.5f;
    m[2] = m[2] + (x.z - m[2]) * 0.5f;
    m[3] = m[3] + (x.w - m[3]) * 0.5f;
    s.x = (m[0] - 1.0f > 0.0f) ? 1.0f : 0.0f;
    s.y = (m[1] - 1.0f > 0.0f) ? 1.0f : 0.0f;
    s.z = (m[2] - 1.0f > 0.0f) ? 1.0f : 0.0f;
    s.w = (m[3] - 1.0f > 0.0f) ? 1.0f : 0.0f;
    m[0] = (s.x != 0.0f) ? 0.0f : m[0];
    m[1] = (s.y != 0.0f) ? 0.0f : m[1];
    m[2] = (s.z != 0.0f) ? 0.0f : m[2];
    m[3] = (s.w != 0.0f) ? 0.0f : m[3];
    return s;
}

__global__ __launch_bounds__(128) void lif_fwd_kernel(
    const float4* __restrict__ X, float4* __restrict__ out)
{
    // 4 blocks per b-row; each block covers 512 consecutive float4 (8 KB).
    // Wave w's 4 loads cover 4 consecutive 1 KB chunks: thread owns columns
    // col0 + {0,64,128,192} (lane-stride-64 interleave keeps each
    // global_load_dwordx4 unit-stride across the 64 lanes).
    const int b       = blockIdx.x >> 2;
    const int quarter = blockIdx.x & 3;
    const int wave    = threadIdx.x >> 6;
    const int lane    = threadIdx.x & 63;
    const int col0    = quarter * 512 + wave * 256 + lane;
    const size_t base = (size_t)b * (size_t)TN4 + (size_t)col0;

    const float4* p0 = X + base;
    const float4* p1 = p0 + 64;
    const float4* p2 = p0 + 128;
    const float4* p3 = p0 + 192;
    float4* q = out + base;

    float m[16];
#pragma unroll
    for (int i = 0; i < 16; ++i) m[i] = 0.f;

    for (int t = 0; t < T_STEPS; ++t) {
        float4 x0, x1, x2, x3;
        // 4 sequential 1 KB loads + drain in ONE asm block (race-free).
        asm volatile(
            "global_load_dwordx4 %0, %4, off\n\t"
            "global_load_dwordx4 %1, %5, off\n\t"
            "global_load_dwordx4 %2, %6, off\n\t"
            "global_load_dwordx4 %3, %7, off\n\t"
            "s_waitcnt vmcnt(0)"
            : "=&v"(x0), "=&v"(x1), "=&v"(x2), "=&v"(x3)
            : "v"(p0), "v"(p1), "v"(p2), "v"(p3)
            : "memory");

        // serial scan update; stores are sequential 1 KB runs too
        q[0]   = lif_step4(x0, m + 0);
        q[64]  = lif_step4(x1, m + 4);
        q[128] = lif_step4(x2, m + 8);
        q[192] = lif_step4(x3, m + 12);

        p0 += N4; p1 += N4; p2 += N4; p3 += N4; q += N4;
    }
}

extern "C" void kernel_launch(void* const* d_in, const int* in_sizes, int n_in,
                              void* d_out, int out_size, void* d_ws, size_t ws_size,
                              hipStream_t stream) {
    const float4* X = (const float4*)d_in[0];
    float4* out = (float4*)d_out;

    const int total = in_sizes[0];          // B*T*N = 33554432
    const int B = total / (T_STEPS * 8192); // 128

    const int block = 128;
    const int grid = B * 4;                 // 512 blocks, 2 per CU

    lif_fwd_kernel<<<grid, block, 0, stream>>>(X, out);
}

// Round 10
// 231.887 us; speedup vs baseline: 1.0123x; 1.0123x over previous
//
#include <hip/hip_runtime.h>

// LIF forward: X [B, T, N] fp32 -> spikes [B, T, N] fp32. B=128,T=32,N=8192.
//   mem = mem + (x - mem)/2 ; spike = (mem-1 > 0) ; mem = spike ? 0 : mem
// Memory-bound: 268 MB user traffic; best so far ~72 us (R3) = 3.7 TB/s eff.
// Falsified theories: MLP depth (R5/R8 forced 16KB/wave in flight: neutral),
//   per-lane width (R8 dwordx4: neutral), occupancy (R3 32w/CU vs R8 16w/CU:
//   same), stream order (R9 8KB contiguous runs: neutral).
// R10 tests the two remaining mechanisms together:
//   (a) PHASE-LOCK: waves start synchronized; every variant alternates
//       all-loads-outstanding <-> zero-outstanding compute phases in
//       lockstep, so CU-level MLP oscillates. Stagger wave starts ~0-8k
//       cycles via a wave-uniform s_sleep ladder (s_sleep imm is required
//       to be a compile-time constant -> binary if-chain).
//   (b) WRITE L2 THRASH: 134 MB spike stores allocate through 32 MB L2,
//       evicting the restore-warmed X lines (FETCH=65MB shows 50% of reads
//       are cache hits). Nontemporal stores keep the write stream out of
//       the cache and protect the read hits.

typedef float v2f __attribute__((ext_vector_type(2)));

#define T_STEPS 32
#define N2 4096            // N/2
#define TN2 (T_STEPS * N2)

__global__ __launch_bounds__(256) void lif_fwd_kernel(
    const float2* __restrict__ X, float2* __restrict__ out)
{
    // ---- wave-uniform start stagger: slot in [0,32), sleep slot*4 units
    // (1 unit ~ 64 cycles) => 0..~8k cycles spread, ~ one loaded-latency
    // period. All branches are wave-uniform (no divergence).
    {
        const int slot = ((threadIdx.x >> 6) + ((blockIdx.x & 7) << 2)) & 31;
        if (slot & 1)  __builtin_amdgcn_s_sleep(4);
        if (slot & 2)  __builtin_amdgcn_s_sleep(8);
        if (slot & 4)  __builtin_amdgcn_s_sleep(16);
        if (slot & 8)  __builtin_amdgcn_s_sleep(32);
        if (slot & 16) __builtin_amdgcn_s_sleep(64);
    }

    const int idx = blockIdx.x * blockDim.x + threadIdx.x;  // over B * N2
    const int b = idx >> 12;          // / N2
    const int n = idx & (N2 - 1);
    const size_t base = (size_t)b * (size_t)TN2 + (size_t)n;

    const float2* __restrict__ px = X + base;
    v2f* po = (v2f*)(out + base);

    float m0 = 0.f, m1 = 0.f;

    // one-step prefetch (R3 structure — best known at ~72 us)
    float2 x = px[0];

#pragma unroll
    for (int t = 0; t < T_STEPS; ++t) {
        float2 xn;
        if (t + 1 < T_STEPS) xn = px[(size_t)(t + 1) * (size_t)N2];

        // exact reference order: mem += (x - mem) * 0.5 ; threshold 1.0
        m0 = m0 + (x.x - m0) * 0.5f;
        m1 = m1 + (x.y - m1) * 0.5f;

        v2f s;
        s.x = (m0 - 1.0f > 0.0f) ? 1.0f : 0.0f;
        s.y = (m1 - 1.0f > 0.0f) ? 1.0f : 0.0f;

        m0 = (s.x != 0.0f) ? 0.0f : m0;
        m1 = (s.y != 0.0f) ? 0.0f : m1;

        // streaming store: don't allocate spike lines in L2
        __builtin_nontemporal_store(s, po + (size_t)t * (size_t)N2);
        x = xn;
    }
}

extern "C" void kernel_launch(void* const* d_in, const int* in_sizes, int n_in,
                              void* d_out, int out_size, void* d_ws, size_t ws_size,
                              hipStream_t stream) {
    const float2* X = (const float2*)d_in[0];
    float2* out = (float2*)d_out;

    const int total = in_sizes[0];          // B*T*N = 33554432
    const int B = total / (T_STEPS * 8192); // 128
    const int nthreads = B * N2;            // 524288

    const int block = 256;
    const int grid = (nthreads + block - 1) / block;  // 2048

    lif_fwd_kernel<<<grid, block, 0, stream>>>(X, out);
}